// Round 3
// baseline (1136.328 us; speedup 1.0000x reference)
//
#include <hip/hip_runtime.h>

#define F 128

typedef short s16x8 __attribute__((ext_vector_type(8)));
typedef float f32x4 __attribute__((ext_vector_type(4)));

__device__ __forceinline__ short f2bf(float f){
  unsigned u = __float_as_uint(f);
  u = u + 0x7FFFu + ((u >> 16) & 1u);   // round-to-nearest-even
  return (short)(u >> 16);
}
__device__ __forceinline__ unsigned fenc(float f){   // order-preserving float->uint
  unsigned u = __float_as_uint(f);
  return (u & 0x80000000u) ? ~u : (u | 0x80000000u);
}
__device__ __forceinline__ float fdec(unsigned u){
  return (u & 0x80000000u) ? __uint_as_float(u & 0x7fffffffu) : __uint_as_float(~u);
}

// ---------------- init: amax=-inf (encoded), denom=0 ----------------
__global__ void init_kernel(unsigned* __restrict__ amax, float* __restrict__ denom, int N){
  int i = blockIdx.x * 256 + threadIdx.x;
  if (i < N){ amax[i] = 0x007FFFFFu; denom[i] = 0.0f; }  // 0x007FFFFF == fenc(-inf)
}

// ---------------- pack weights: packW[g][col][k] = bf16(W_g[k][col]) ----------------
// g: 0 = Wa1 rows 0..127 (src part), 1 = rows 128..255 (dst), 2 = rows 256..383 (gh), 3 = We1
__global__ void pack_kernel(const float* __restrict__ Wa1, const float* __restrict__ We1,
                            short* __restrict__ packW){
  int col = blockIdx.x, g = blockIdx.y, k = threadIdx.x;
  float v;
  if      (g == 0) v = Wa1[k*F + col];
  else if (g == 1) v = Wa1[(F + k)*F + col];
  else if (g == 2) v = Wa1[(2*F + k)*F + col];
  else             v = We1[k*F + col];
  packW[((size_t)g*F + col)*F + k] = f2bf(v);
}

// ---------------- node GEMM: Psrc, Pdst, and epsp1 = 1 + eps ----------------
__global__ __launch_bounds__(256) void node_gemm_kernel(
    const float* __restrict__ nf, const short* __restrict__ packW,
    float* __restrict__ Psrc, float* __restrict__ Pdst, float* __restrict__ epsp1,
    const float* __restrict__ be1, const float* __restrict__ We2, const float* __restrict__ be2,
    int N)
{
  int g = blockIdx.y;                 // 0: src-proj, 1: dst-proj, 2: We1 path
  int m = (g == 2) ? 3 : g;           // weight matrix index in packW
  int tid = threadIdx.x;
  int wave = tid >> 6, lane = tid & 63;
  int lrow = lane & 15, lk8 = lane >> 4;

  const short* W = packW + (size_t)m*F*F;
  s16x8 bfrag[2][4];
  float we2v[2], be1v[2];
  for (int cg = 0; cg < 2; ++cg){
    int col = wave*32 + cg*16 + lrow;
    for (int kc = 0; kc < 4; ++kc)
      bfrag[cg][kc] = *(const s16x8*)(W + (size_t)col*F + kc*32 + lk8*8);
    if (g == 2){ we2v[cg] = We2[col]; be1v[cg] = be1[col]; }
  }
  float be2v = (g == 2) ? be2[0] : 0.0f;

  __shared__ float red[4][16][16];
  int ntiles = (N + 15) >> 4;
  for (int t = blockIdx.x; t < ntiles; t += gridDim.x){
    int n0 = t * 16;
    int arow = n0 + lrow; if (arow >= N) arow = N - 1;
    const float* ap = nf + (size_t)arow*F;
    s16x8 afrag[4];
    for (int kc = 0; kc < 4; ++kc){
      float4 x0 = *(const float4*)(ap + kc*32 + lk8*8);
      float4 x1 = *(const float4*)(ap + kc*32 + lk8*8 + 4);
      s16x8 a;
      a[0]=f2bf(x0.x); a[1]=f2bf(x0.y); a[2]=f2bf(x0.z); a[3]=f2bf(x0.w);
      a[4]=f2bf(x1.x); a[5]=f2bf(x1.y); a[6]=f2bf(x1.z); a[7]=f2bf(x1.w);
      afrag[kc] = a;
    }
    f32x4 acc0 = {0,0,0,0}, acc1 = {0,0,0,0};
    for (int kc = 0; kc < 4; ++kc){
      acc0 = __builtin_amdgcn_mfma_f32_16x16x32_bf16(afrag[kc], bfrag[0][kc], acc0, 0,0,0);
      acc1 = __builtin_amdgcn_mfma_f32_16x16x32_bf16(afrag[kc], bfrag[1][kc], acc1, 0,0,0);
    }
    if (g < 2){
      float* P = (g == 0) ? Psrc : Pdst;
      for (int j = 0; j < 4; ++j){
        int n = n0 + lk8*4 + j;
        if (n < N){
          P[(size_t)n*F + wave*32 + lrow]      = acc0[j];
          P[(size_t)n*F + wave*32 + 16 + lrow] = acc1[j];
        }
      }
    } else {
      float psum[4];
      for (int j = 0; j < 4; ++j){
        float h0 = acc0[j] + be1v[0];
        float h1 = acc1[j] + be1v[1];
        float s = 0.0f;
        if (h0 > 0.0f) s += h0 * we2v[0];
        if (h1 > 0.0f) s += h1 * we2v[1];
        psum[j] = s;
      }
      __syncthreads();
      for (int j = 0; j < 4; ++j) red[wave][lk8*4 + j][lrow] = psum[j];
      __syncthreads();
      int r = tid >> 4, c = tid & 15;
      float s2 = red[0][r][c] + red[1][r][c] + red[2][r][c] + red[3][r][c];
      s2 += __shfl_xor(s2, 1); s2 += __shfl_xor(s2, 2);
      s2 += __shfl_xor(s2, 4); s2 += __shfl_xor(s2, 8);
      if (c == 0 && n0 + r < N) epsp1[n0 + r] = 1.0f + s2 + be2v;
    }
  }
}

// ---------------- edge GEMM: a[e] = relu(gh@W + Psrc[src] + Pdst[dst] + ba1) . Wa2 + ba2 ----------------
__global__ __launch_bounds__(256) void edge_gemm_kernel(
    const float* __restrict__ gh, const short* __restrict__ Wt,
    const float* __restrict__ Psrc, const float* __restrict__ Pdst,
    const int* __restrict__ src, const int* __restrict__ dst,
    const float* __restrict__ ba1, const float* __restrict__ Wa2, const float* __restrict__ ba2,
    float* __restrict__ av, int E)
{
  int tid = threadIdx.x;
  int wave = tid >> 6, lane = tid & 63;
  int lrow = lane & 15, lk8 = lane >> 4;

  s16x8 bfrag[2][4];
  float wa2v[2], ba1v[2];
  for (int cg = 0; cg < 2; ++cg){
    int col = wave*32 + cg*16 + lrow;
    wa2v[cg] = Wa2[col];
    ba1v[cg] = ba1[col];
    for (int kc = 0; kc < 4; ++kc)
      bfrag[cg][kc] = *(const s16x8*)(Wt + (size_t)col*F + kc*32 + lk8*8);
  }
  float ba2v = ba2[0];

  __shared__ float red[4][16][16];
  int ntiles = (E + 15) >> 4;
  for (int t = blockIdx.x; t < ntiles; t += gridDim.x){
    int e0 = t * 16;
    int arow = e0 + lrow; if (arow >= E) arow = E - 1;
    const float* gp = gh + (size_t)arow*F;
    s16x8 afrag[4];
    for (int kc = 0; kc < 4; ++kc){
      float4 x0 = *(const float4*)(gp + kc*32 + lk8*8);
      float4 x1 = *(const float4*)(gp + kc*32 + lk8*8 + 4);
      s16x8 a;
      a[0]=f2bf(x0.x); a[1]=f2bf(x0.y); a[2]=f2bf(x0.z); a[3]=f2bf(x0.w);
      a[4]=f2bf(x1.x); a[5]=f2bf(x1.y); a[6]=f2bf(x1.z); a[7]=f2bf(x1.w);
      afrag[kc] = a;
    }
    f32x4 acc0 = {0,0,0,0}, acc1 = {0,0,0,0};
    for (int kc = 0; kc < 4; ++kc){
      acc0 = __builtin_amdgcn_mfma_f32_16x16x32_bf16(afrag[kc], bfrag[0][kc], acc0, 0,0,0);
      acc1 = __builtin_amdgcn_mfma_f32_16x16x32_bf16(afrag[kc], bfrag[1][kc], acc1, 0,0,0);
    }
    float psum[4];
    for (int j = 0; j < 4; ++j){
      int e = e0 + lk8*4 + j;
      int ec = (e < E) ? e : E - 1;
      int s = src[ec], d = dst[ec];
      int col0 = wave*32 + lrow, col1 = wave*32 + 16 + lrow;
      float h0 = acc0[j] + Psrc[(size_t)s*F + col0] + Pdst[(size_t)d*F + col0] + ba1v[0];
      float h1 = acc1[j] + Psrc[(size_t)s*F + col1] + Pdst[(size_t)d*F + col1] + ba1v[1];
      float ps = 0.0f;
      if (h0 > 0.0f) ps += h0 * wa2v[0];
      if (h1 > 0.0f) ps += h1 * wa2v[1];
      psum[j] = ps;
    }
    __syncthreads();
    for (int j = 0; j < 4; ++j) red[wave][lk8*4 + j][lrow] = psum[j];
    __syncthreads();
    int r = tid >> 4, c = tid & 15;
    float s2 = red[0][r][c] + red[1][r][c] + red[2][r][c] + red[3][r][c];
    s2 += __shfl_xor(s2, 1); s2 += __shfl_xor(s2, 2);
    s2 += __shfl_xor(s2, 4); s2 += __shfl_xor(s2, 8);
    if (c == 0 && e0 + r < E) av[e0 + r] = s2 + ba2v;
  }
}

// ---------------- segment max (encoded uint atomicMax) ----------------
__global__ void amax_kernel(const float* __restrict__ av, const int* __restrict__ dst,
                            unsigned* __restrict__ amax, int E){
  int e = blockIdx.x * 256 + threadIdx.x;
  if (e >= E) return;
  atomicMax(&amax[dst[e]], fenc(av[e]));
}

// ---------------- ex = exp(a - amax[dst]); denom += ex ----------------
__global__ void exden_kernel(const float* __restrict__ av, const int* __restrict__ dst,
                             const unsigned* __restrict__ amax,
                             float* __restrict__ exv, float* __restrict__ denom, int E){
  int e = blockIdx.x * 256 + threadIdx.x;
  if (e >= E) return;
  int d = dst[e];
  float ex = expf(av[e] - fdec(amax[d]));
  exv[e] = ex;
  atomicAdd(&denom[d], ex);
}

// ---------------- hv scatter: out[dst] += alpha * h_src * gh ----------------
__global__ void scatter_kernel(const float* __restrict__ gh, const float* __restrict__ nf,
                               const int* __restrict__ src, const int* __restrict__ dst,
                               const float* __restrict__ exv, const float* __restrict__ denom,
                               float* __restrict__ out, int E){
  int gid = blockIdx.x * 256 + threadIdx.x;
  int e = gid >> 5;
  if (e >= E) return;
  int q = gid & 31;
  int d = dst[e];
  float alpha = exv[e] / denom[d];
  float4 g4 = *(const float4*)(gh + (size_t)e*F + q*4);
  float4 h4 = *(const float4*)(nf + (size_t)src[e]*F + q*4);
  float* ob = out + (size_t)d*F + q*4;
  atomicAdd(ob + 0, alpha * g4.x * h4.x);
  atomicAdd(ob + 1, alpha * g4.y * h4.y);
  atomicAdd(ob + 2, alpha * g4.z * h4.z);
  atomicAdd(ob + 3, alpha * g4.w * h4.w);
}

// ---------------- final: out = (1+eps)*hv + nf ----------------
__global__ void final_kernel(const float* __restrict__ nf, const float* __restrict__ epsp1,
                             float* __restrict__ out, int N){
  int gid = blockIdx.x * 256 + threadIdx.x;
  int n = gid >> 5;
  if (n >= N) return;
  int q = gid & 31;
  float ep = epsp1[n];
  float4* o = (float4*)(out + (size_t)n*F + q*4);
  const float4* x = (const float4*)(nf + (size_t)n*F + q*4);
  float4 ov = *o, xv = *x;
  ov.x = ep*ov.x + xv.x; ov.y = ep*ov.y + xv.y;
  ov.z = ep*ov.z + xv.z; ov.w = ep*ov.w + xv.w;
  *o = ov;
}

extern "C" void kernel_launch(void* const* d_in, const int* in_sizes, int n_in,
                              void* d_out, int out_size, void* d_ws, size_t ws_size,
                              hipStream_t stream)
{
  const float* nf  = (const float*)d_in[0];
  const float* gh  = (const float*)d_in[1];
  const int*   src = (const int*)d_in[2];
  const int*   dst = (const int*)d_in[3];
  const float* Wa1 = (const float*)d_in[4];
  const float* ba1 = (const float*)d_in[5];
  const float* Wa2 = (const float*)d_in[6];
  const float* ba2 = (const float*)d_in[7];
  const float* We1 = (const float*)d_in[8];
  const float* be1 = (const float*)d_in[9];
  const float* We2 = (const float*)d_in[10];
  const float* be2 = (const float*)d_in[11];
  int N = in_sizes[0] / F;
  int E = in_sizes[2];
  float* out = (float*)d_out;

  char* w = (char*)d_ws;
  auto alloc = [&](size_t bytes) -> char* {
    char* p = w; w += (bytes + 255) & ~(size_t)255; return p;
  };
  short*    packW = (short*)   alloc((size_t)4*F*F*sizeof(short));
  float*    Psrc  = (float*)   alloc((size_t)N*F*sizeof(float));
  float*    Pdst  = (float*)   alloc((size_t)N*F*sizeof(float));
  float*    epsp1 = (float*)   alloc((size_t)N*sizeof(float));
  float*    av    = (float*)   alloc((size_t)E*sizeof(float));
  float*    exv   = (float*)   alloc((size_t)E*sizeof(float));
  unsigned* amax  = (unsigned*)alloc((size_t)N*sizeof(unsigned));
  float*    denom = (float*)   alloc((size_t)N*sizeof(float));

  hipMemsetAsync(d_out, 0, (size_t)N*F*sizeof(float), stream);
  init_kernel<<<(N + 255)/256, 256, 0, stream>>>(amax, denom, N);
  pack_kernel<<<dim3(F, 4), F, 0, stream>>>(Wa1, We1, packW);
  node_gemm_kernel<<<dim3(512, 3), 256, 0, stream>>>(nf, packW, Psrc, Pdst, epsp1,
                                                     be1, We2, be2, N);
  edge_gemm_kernel<<<2048, 256, 0, stream>>>(gh, packW + (size_t)2*F*F, Psrc, Pdst,
                                             src, dst, ba1, Wa2, ba2, av, E);
  amax_kernel<<<(E + 255)/256, 256, 0, stream>>>(av, dst, amax, E);
  exden_kernel<<<(E + 255)/256, 256, 0, stream>>>(av, dst, amax, exv, denom, E);
  scatter_kernel<<<((size_t)E*32 + 255)/256, 256, 0, stream>>>(gh, nf, src, dst,
                                                               exv, denom, out, E);
  final_kernel<<<((size_t)N*32 + 255)/256, 256, 0, stream>>>(nf, epsp1, out, N);
}

// Round 4
// 662.302 us; speedup vs baseline: 1.7157x; 1.7157x over previous
//
#include <hip/hip_runtime.h>

#define F 128

typedef short s16x8 __attribute__((ext_vector_type(8)));
typedef float f32x4 __attribute__((ext_vector_type(4)));

__device__ __forceinline__ short f2bf(float f){
  unsigned u = __float_as_uint(f);
  u = u + 0x7FFFu + ((u >> 16) & 1u);   // round-to-nearest-even
  return (short)(u >> 16);
}
__device__ __forceinline__ unsigned fenc(float f){   // order-preserving float->uint
  unsigned u = __float_as_uint(f);
  return (u & 0x80000000u) ? ~u : (u | 0x80000000u);
}
__device__ __forceinline__ float fdec(unsigned u){
  return (u & 0x80000000u) ? __uint_as_float(u & 0x7fffffffu) : __uint_as_float(~u);
}

// ---------------- init: amax=-inf (encoded), denom=0, cnt=0 ----------------
__global__ void init_kernel(unsigned* __restrict__ amax, float* __restrict__ denom,
                            int* __restrict__ cnt, int N){
  int i = blockIdx.x * 256 + threadIdx.x;
  if (i < N){ amax[i] = 0x007FFFFFu; denom[i] = 0.0f; cnt[i] = 0; }
}

// ---------------- pack weights: packW[g][col][k] = bf16(W_g[k][col]) ----------------
__global__ void pack_kernel(const float* __restrict__ Wa1, const float* __restrict__ We1,
                            short* __restrict__ packW){
  int col = blockIdx.x, g = blockIdx.y, k = threadIdx.x;
  float v;
  if      (g == 0) v = Wa1[k*F + col];
  else if (g == 1) v = Wa1[(F + k)*F + col];
  else if (g == 2) v = Wa1[(2*F + k)*F + col];
  else             v = We1[k*F + col];
  packW[((size_t)g*F + col)*F + k] = f2bf(v);
}

// ---------------- node GEMM: Psrc, Pdst, and epsp1 = 1 + eps ----------------
__global__ __launch_bounds__(256) void node_gemm_kernel(
    const float* __restrict__ nf, const short* __restrict__ packW,
    float* __restrict__ Psrc, float* __restrict__ Pdst, float* __restrict__ epsp1,
    const float* __restrict__ be1, const float* __restrict__ We2, const float* __restrict__ be2,
    int N)
{
  int g = blockIdx.y;                 // 0: src-proj, 1: dst-proj, 2: We1 path
  int m = (g == 2) ? 3 : g;
  int tid = threadIdx.x;
  int wave = tid >> 6, lane = tid & 63;
  int lrow = lane & 15, lk8 = lane >> 4;

  const short* W = packW + (size_t)m*F*F;
  s16x8 bfrag[2][4];
  float we2v[2], be1v[2];
  for (int cg = 0; cg < 2; ++cg){
    int col = wave*32 + cg*16 + lrow;
    for (int kc = 0; kc < 4; ++kc)
      bfrag[cg][kc] = *(const s16x8*)(W + (size_t)col*F + kc*32 + lk8*8);
    if (g == 2){ we2v[cg] = We2[col]; be1v[cg] = be1[col]; }
  }
  float be2v = (g == 2) ? be2[0] : 0.0f;

  __shared__ float red[4][16][16];
  int ntiles = (N + 15) >> 4;
  for (int t = blockIdx.x; t < ntiles; t += gridDim.x){
    int n0 = t * 16;
    int arow = n0 + lrow; if (arow >= N) arow = N - 1;
    const float* ap = nf + (size_t)arow*F;
    s16x8 afrag[4];
    for (int kc = 0; kc < 4; ++kc){
      float4 x0 = *(const float4*)(ap + kc*32 + lk8*8);
      float4 x1 = *(const float4*)(ap + kc*32 + lk8*8 + 4);
      s16x8 a;
      a[0]=f2bf(x0.x); a[1]=f2bf(x0.y); a[2]=f2bf(x0.z); a[3]=f2bf(x0.w);
      a[4]=f2bf(x1.x); a[5]=f2bf(x1.y); a[6]=f2bf(x1.z); a[7]=f2bf(x1.w);
      afrag[kc] = a;
    }
    f32x4 acc0 = {0,0,0,0}, acc1 = {0,0,0,0};
    for (int kc = 0; kc < 4; ++kc){
      acc0 = __builtin_amdgcn_mfma_f32_16x16x32_bf16(afrag[kc], bfrag[0][kc], acc0, 0,0,0);
      acc1 = __builtin_amdgcn_mfma_f32_16x16x32_bf16(afrag[kc], bfrag[1][kc], acc1, 0,0,0);
    }
    if (g < 2){
      float* P = (g == 0) ? Psrc : Pdst;
      for (int j = 0; j < 4; ++j){
        int n = n0 + lk8*4 + j;
        if (n < N){
          P[(size_t)n*F + wave*32 + lrow]      = acc0[j];
          P[(size_t)n*F + wave*32 + 16 + lrow] = acc1[j];
        }
      }
    } else {
      float psum[4];
      for (int j = 0; j < 4; ++j){
        float h0 = acc0[j] + be1v[0];
        float h1 = acc1[j] + be1v[1];
        float s = 0.0f;
        if (h0 > 0.0f) s += h0 * we2v[0];
        if (h1 > 0.0f) s += h1 * we2v[1];
        psum[j] = s;
      }
      __syncthreads();
      for (int j = 0; j < 4; ++j) red[wave][lk8*4 + j][lrow] = psum[j];
      __syncthreads();
      int r = tid >> 4, c = tid & 15;
      float s2 = red[0][r][c] + red[1][r][c] + red[2][r][c] + red[3][r][c];
      s2 += __shfl_xor(s2, 1); s2 += __shfl_xor(s2, 2);
      s2 += __shfl_xor(s2, 4); s2 += __shfl_xor(s2, 8);
      if (c == 0 && n0 + r < N) epsp1[n0 + r] = 1.0f + s2 + be2v;
    }
  }
}

// ---------------- edge GEMM ----------------
__global__ __launch_bounds__(256) void edge_gemm_kernel(
    const float* __restrict__ gh, const short* __restrict__ Wt,
    const float* __restrict__ Psrc, const float* __restrict__ Pdst,
    const int* __restrict__ src, const int* __restrict__ dst,
    const float* __restrict__ ba1, const float* __restrict__ Wa2, const float* __restrict__ ba2,
    float* __restrict__ av, int E)
{
  int tid = threadIdx.x;
  int wave = tid >> 6, lane = tid & 63;
  int lrow = lane & 15, lk8 = lane >> 4;

  s16x8 bfrag[2][4];
  float wa2v[2], ba1v[2];
  for (int cg = 0; cg < 2; ++cg){
    int col = wave*32 + cg*16 + lrow;
    wa2v[cg] = Wa2[col];
    ba1v[cg] = ba1[col];
    for (int kc = 0; kc < 4; ++kc)
      bfrag[cg][kc] = *(const s16x8*)(Wt + (size_t)col*F + kc*32 + lk8*8);
  }
  float ba2v = ba2[0];

  __shared__ float red[4][16][16];
  int ntiles = (E + 15) >> 4;
  for (int t = blockIdx.x; t < ntiles; t += gridDim.x){
    int e0 = t * 16;
    int arow = e0 + lrow; if (arow >= E) arow = E - 1;
    const float* gp = gh + (size_t)arow*F;
    s16x8 afrag[4];
    for (int kc = 0; kc < 4; ++kc){
      float4 x0 = *(const float4*)(gp + kc*32 + lk8*8);
      float4 x1 = *(const float4*)(gp + kc*32 + lk8*8 + 4);
      s16x8 a;
      a[0]=f2bf(x0.x); a[1]=f2bf(x0.y); a[2]=f2bf(x0.z); a[3]=f2bf(x0.w);
      a[4]=f2bf(x1.x); a[5]=f2bf(x1.y); a[6]=f2bf(x1.z); a[7]=f2bf(x1.w);
      afrag[kc] = a;
    }
    f32x4 acc0 = {0,0,0,0}, acc1 = {0,0,0,0};
    for (int kc = 0; kc < 4; ++kc){
      acc0 = __builtin_amdgcn_mfma_f32_16x16x32_bf16(afrag[kc], bfrag[0][kc], acc0, 0,0,0);
      acc1 = __builtin_amdgcn_mfma_f32_16x16x32_bf16(afrag[kc], bfrag[1][kc], acc1, 0,0,0);
    }
    float psum[4];
    for (int j = 0; j < 4; ++j){
      int e = e0 + lk8*4 + j;
      int ec = (e < E) ? e : E - 1;
      int s = src[ec], d = dst[ec];
      int col0 = wave*32 + lrow, col1 = wave*32 + 16 + lrow;
      float h0 = acc0[j] + Psrc[(size_t)s*F + col0] + Pdst[(size_t)d*F + col0] + ba1v[0];
      float h1 = acc1[j] + Psrc[(size_t)s*F + col1] + Pdst[(size_t)d*F + col1] + ba1v[1];
      float ps = 0.0f;
      if (h0 > 0.0f) ps += h0 * wa2v[0];
      if (h1 > 0.0f) ps += h1 * wa2v[1];
      psum[j] = ps;
    }
    __syncthreads();
    for (int j = 0; j < 4; ++j) red[wave][lk8*4 + j][lrow] = psum[j];
    __syncthreads();
    int r = tid >> 4, c = tid & 15;
    float s2 = red[0][r][c] + red[1][r][c] + red[2][r][c] + red[3][r][c];
    s2 += __shfl_xor(s2, 1); s2 += __shfl_xor(s2, 2);
    s2 += __shfl_xor(s2, 4); s2 += __shfl_xor(s2, 8);
    if (c == 0 && e0 + r < E) av[e0 + r] = s2 + ba2v;
  }
}

// ---------------- segment max + degree count ----------------
__global__ void amax_count_kernel(const float* __restrict__ av, const int* __restrict__ dst,
                                  unsigned* __restrict__ amax, int* __restrict__ cnt, int E){
  int e = blockIdx.x * 256 + threadIdx.x;
  if (e >= E) return;
  int d = dst[e];
  atomicMax(&amax[d], fenc(av[e]));
  atomicAdd(&cnt[d], 1);
}

// ---------------- exclusive scan of cnt -> off, cursor (single block) ----------------
__global__ void scan_kernel(const int* __restrict__ cnt, int* __restrict__ off,
                            int* __restrict__ cursor, int N){
  __shared__ int tmp[256];
  __shared__ int carry;
  if (threadIdx.x == 0) carry = 0;
  __syncthreads();
  for (int base = 0; base < N; base += 256){
    int i = base + threadIdx.x;
    int v = (i < N) ? cnt[i] : 0;
    tmp[threadIdx.x] = v;
    for (int s = 1; s < 256; s <<= 1){
      __syncthreads();
      int t = (threadIdx.x >= s) ? tmp[threadIdx.x - s] : 0;
      __syncthreads();
      tmp[threadIdx.x] += t;
    }
    __syncthreads();
    int incl = tmp[threadIdx.x];
    int myoff = carry + incl - v;          // exclusive
    if (i < N){ off[i] = myoff; cursor[i] = myoff; }
    __syncthreads();
    if (threadIdx.x == 255) carry += tmp[255];
    __syncthreads();
  }
  if (threadIdx.x == 0) off[N] = carry;
}

// ---------------- ex = exp(a - amax[dst]); denom += ex; perm fill ----------------
__global__ void exden_fill_kernel(const float* __restrict__ av, const int* __restrict__ dst,
                                  const unsigned* __restrict__ amax,
                                  float* __restrict__ exv, float* __restrict__ denom,
                                  int* __restrict__ cursor, int* __restrict__ perm, int E){
  int e = blockIdx.x * 256 + threadIdx.x;
  if (e >= E) return;
  int d = dst[e];
  float ex = expf(av[e] - fdec(amax[d]));
  exv[e] = ex;
  atomicAdd(&denom[d], ex);
  int pos = atomicAdd(&cursor[d], 1);
  perm[pos] = e;
}

// ---------------- gather + final: out[n] = epsp1[n] * sum(alpha*gh*nf[src]) + nf[n] ----------------
__global__ __launch_bounds__(256) void gather_kernel(
    const float* __restrict__ gh, const float* __restrict__ nf,
    const int* __restrict__ src, const int* __restrict__ perm, const int* __restrict__ off,
    const float* __restrict__ exv, const float* __restrict__ denom,
    const float* __restrict__ epsp1, float* __restrict__ out, int N)
{
  int lane = threadIdx.x & 63;
  int n = blockIdx.x * 4 + (threadIdx.x >> 6);
  if (n >= N) return;
  int start = off[n], end = off[n + 1];
  float rden = 1.0f / denom[n];
  int c = lane * 2;
  float ax = 0.0f, ay = 0.0f;
  for (int base = start; base < end; base += 64){
    int idx = base + lane;
    int mye = 0, mysrc = 0; float mya = 0.0f;
    if (idx < end){
      mye = perm[idx];
      mysrc = src[mye];
      mya = exv[mye] * rden;
    }
    int m = end - base; if (m > 64) m = 64;
    for (int it = 0; it < m; ++it){
      float alpha = __shfl(mya, it);
      int e     = __shfl(mye, it);
      int srow  = __shfl(mysrc, it);
      float2 g = *(const float2*)(gh + (size_t)e*F + c);
      float2 h = *(const float2*)(nf + (size_t)srow*F + c);
      ax += alpha * g.x * h.x;
      ay += alpha * g.y * h.y;
    }
  }
  float ep = epsp1[n];
  float2 x = *(const float2*)(nf + (size_t)n*F + c);
  float2 o;
  o.x = ep * ax + x.x;
  o.y = ep * ay + x.y;
  *(float2*)(out + (size_t)n*F + c) = o;
}

extern "C" void kernel_launch(void* const* d_in, const int* in_sizes, int n_in,
                              void* d_out, int out_size, void* d_ws, size_t ws_size,
                              hipStream_t stream)
{
  const float* nf  = (const float*)d_in[0];
  const float* gh  = (const float*)d_in[1];
  const int*   src = (const int*)d_in[2];
  const int*   dst = (const int*)d_in[3];
  const float* Wa1 = (const float*)d_in[4];
  const float* ba1 = (const float*)d_in[5];
  const float* Wa2 = (const float*)d_in[6];
  const float* ba2 = (const float*)d_in[7];
  const float* We1 = (const float*)d_in[8];
  const float* be1 = (const float*)d_in[9];
  const float* We2 = (const float*)d_in[10];
  const float* be2 = (const float*)d_in[11];
  int N = in_sizes[0] / F;
  int E = in_sizes[2];
  float* out = (float*)d_out;

  char* w = (char*)d_ws;
  auto alloc = [&](size_t bytes) -> char* {
    char* p = w; w += (bytes + 255) & ~(size_t)255; return p;
  };
  short*    packW  = (short*)   alloc((size_t)4*F*F*sizeof(short));
  float*    Psrc   = (float*)   alloc((size_t)N*F*sizeof(float));
  float*    Pdst   = (float*)   alloc((size_t)N*F*sizeof(float));
  float*    epsp1  = (float*)   alloc((size_t)N*sizeof(float));
  float*    av     = (float*)   alloc((size_t)E*sizeof(float));
  float*    exv    = (float*)   alloc((size_t)E*sizeof(float));
  unsigned* amax   = (unsigned*)alloc((size_t)N*sizeof(unsigned));
  float*    denom  = (float*)   alloc((size_t)N*sizeof(float));
  int*      cnt    = (int*)     alloc((size_t)N*sizeof(int));
  int*      off    = (int*)     alloc((size_t)(N+1)*sizeof(int));
  int*      cursor = (int*)     alloc((size_t)N*sizeof(int));
  int*      perm   = (int*)     alloc((size_t)E*sizeof(int));

  init_kernel<<<(N + 255)/256, 256, 0, stream>>>(amax, denom, cnt, N);
  pack_kernel<<<dim3(F, 4), F, 0, stream>>>(Wa1, We1, packW);
  node_gemm_kernel<<<dim3(512, 3), 256, 0, stream>>>(nf, packW, Psrc, Pdst, epsp1,
                                                     be1, We2, be2, N);
  edge_gemm_kernel<<<2048, 256, 0, stream>>>(gh, packW + (size_t)2*F*F, Psrc, Pdst,
                                             src, dst, ba1, Wa2, ba2, av, E);
  amax_count_kernel<<<(E + 255)/256, 256, 0, stream>>>(av, dst, amax, cnt, E);
  scan_kernel<<<1, 256, 0, stream>>>(cnt, off, cursor, N);
  exden_fill_kernel<<<(E + 255)/256, 256, 0, stream>>>(av, dst, amax, exv, denom,
                                                       cursor, perm, E);
  gather_kernel<<<(N + 3)/4, 256, 0, stream>>>(gh, nf, src, perm, off,
                                               exv, denom, epsp1, out, N);
}

// Round 5
// 657.083 us; speedup vs baseline: 1.7294x; 1.0079x over previous
//
#include <hip/hip_runtime.h>

#define F 128

typedef short s16x8 __attribute__((ext_vector_type(8)));
typedef float f32x4 __attribute__((ext_vector_type(4)));

__device__ __forceinline__ short f2bf(float f){
  unsigned u = __float_as_uint(f);
  u = u + 0x7FFFu + ((u >> 16) & 1u);   // round-to-nearest-even
  return (short)(u >> 16);
}
__device__ __forceinline__ float bf2f(short s){
  return __uint_as_float(((unsigned)(unsigned short)s) << 16);
}
__device__ __forceinline__ unsigned fenc(float f){
  unsigned u = __float_as_uint(f);
  return (u & 0x80000000u) ? ~u : (u | 0x80000000u);
}
__device__ __forceinline__ float fdec(unsigned u){
  return (u & 0x80000000u) ? __uint_as_float(u & 0x7fffffffu) : __uint_as_float(~u);
}

// =================== shared kernels ===================

__global__ void pack_kernel(const float* __restrict__ Wa1, const float* __restrict__ We1,
                            short* __restrict__ packW){
  int col = blockIdx.x, g = blockIdx.y, k = threadIdx.x;
  float v;
  if      (g == 0) v = Wa1[k*F + col];
  else if (g == 1) v = Wa1[(F + k)*F + col];
  else if (g == 2) v = Wa1[(2*F + k)*F + col];
  else             v = We1[k*F + col];
  packW[((size_t)g*F + col)*F + k] = f2bf(v);
}

__global__ __launch_bounds__(256) void node_gemm_kernel(
    const float* __restrict__ nf, const short* __restrict__ packW,
    float* __restrict__ Psrc, float* __restrict__ Pdst, float* __restrict__ epsp1,
    const float* __restrict__ be1, const float* __restrict__ We2, const float* __restrict__ be2,
    int N)
{
  int g = blockIdx.y;                 // 0: src-proj, 1: dst-proj, 2: We1 path
  int m = (g == 2) ? 3 : g;
  int tid = threadIdx.x;
  int wave = tid >> 6, lane = tid & 63;
  int lrow = lane & 15, lk8 = lane >> 4;

  const short* W = packW + (size_t)m*F*F;
  s16x8 bfrag[2][4];
  float we2v[2], be1v[2];
  for (int cg = 0; cg < 2; ++cg){
    int col = wave*32 + cg*16 + lrow;
    for (int kc = 0; kc < 4; ++kc)
      bfrag[cg][kc] = *(const s16x8*)(W + (size_t)col*F + kc*32 + lk8*8);
    if (g == 2){ we2v[cg] = We2[col]; be1v[cg] = be1[col]; }
  }
  float be2v = (g == 2) ? be2[0] : 0.0f;

  __shared__ float red[4][16][17];
  int ntiles = (N + 15) >> 4;
  for (int t = blockIdx.x; t < ntiles; t += gridDim.x){
    int n0 = t * 16;
    int arow = n0 + lrow; if (arow >= N) arow = N - 1;
    const float* ap = nf + (size_t)arow*F;
    s16x8 afrag[4];
    for (int kc = 0; kc < 4; ++kc){
      float4 x0 = *(const float4*)(ap + kc*32 + lk8*8);
      float4 x1 = *(const float4*)(ap + kc*32 + lk8*8 + 4);
      s16x8 a;
      a[0]=f2bf(x0.x); a[1]=f2bf(x0.y); a[2]=f2bf(x0.z); a[3]=f2bf(x0.w);
      a[4]=f2bf(x1.x); a[5]=f2bf(x1.y); a[6]=f2bf(x1.z); a[7]=f2bf(x1.w);
      afrag[kc] = a;
    }
    f32x4 acc0 = {0,0,0,0}, acc1 = {0,0,0,0};
    for (int kc = 0; kc < 4; ++kc){
      acc0 = __builtin_amdgcn_mfma_f32_16x16x32_bf16(afrag[kc], bfrag[0][kc], acc0, 0,0,0);
      acc1 = __builtin_amdgcn_mfma_f32_16x16x32_bf16(afrag[kc], bfrag[1][kc], acc1, 0,0,0);
    }
    if (g < 2){
      float* P = (g == 0) ? Psrc : Pdst;
      for (int j = 0; j < 4; ++j){
        int n = n0 + lk8*4 + j;
        if (n < N){
          P[(size_t)n*F + wave*32 + lrow]      = acc0[j];
          P[(size_t)n*F + wave*32 + 16 + lrow] = acc1[j];
        }
      }
    } else {
      float psum[4];
      for (int j = 0; j < 4; ++j){
        float h0 = acc0[j] + be1v[0];
        float h1 = acc1[j] + be1v[1];
        float s = 0.0f;
        if (h0 > 0.0f) s += h0 * we2v[0];
        if (h1 > 0.0f) s += h1 * we2v[1];
        psum[j] = s;
      }
      __syncthreads();
      for (int j = 0; j < 4; ++j) red[wave][lk8*4 + j][lrow] = psum[j];
      __syncthreads();
      int r = tid >> 4, c = tid & 15;
      float s2 = red[0][r][c] + red[1][r][c] + red[2][r][c] + red[3][r][c];
      s2 += __shfl_xor(s2, 1); s2 += __shfl_xor(s2, 2);
      s2 += __shfl_xor(s2, 4); s2 += __shfl_xor(s2, 8);
      if (c == 0 && n0 + r < N) epsp1[n0 + r] = 1.0f + s2 + be2v;
    }
  }
}

__global__ void scan_kernel(const int* __restrict__ cnt, int* __restrict__ off,
                            int* __restrict__ cursor, int N){
  __shared__ int tmp[256];
  __shared__ int carry;
  if (threadIdx.x == 0) carry = 0;
  __syncthreads();
  for (int base = 0; base < N; base += 256){
    int i = base + threadIdx.x;
    int v = (i < N) ? cnt[i] : 0;
    tmp[threadIdx.x] = v;
    for (int s = 1; s < 256; s <<= 1){
      __syncthreads();
      int t = (threadIdx.x >= s) ? tmp[threadIdx.x - s] : 0;
      __syncthreads();
      tmp[threadIdx.x] += t;
    }
    __syncthreads();
    int incl = tmp[threadIdx.x];
    int myoff = carry + incl - v;          // exclusive
    if (i < N){ off[i] = myoff; cursor[i] = myoff; }
    __syncthreads();
    if (threadIdx.x == 255) carry += tmp[255];
    __syncthreads();
  }
  if (threadIdx.x == 0) off[N] = carry;
}

// =================== sorted-path kernels ===================

__global__ void initc_kernel(int* __restrict__ cnt, int N){
  int i = blockIdx.x * 256 + threadIdx.x;
  if (i < N) cnt[i] = 0;
}

__global__ void count_kernel(const int* __restrict__ dst, int* __restrict__ cnt, int E){
  int e = blockIdx.x * 256 + threadIdx.x;
  if (e < E) atomicAdd(&cnt[dst[e]], 1);
}

__global__ void fill_sorted_kernel(const int* __restrict__ src, const int* __restrict__ dst,
                                   int* __restrict__ cursor, int* __restrict__ eperm,
                                   int* __restrict__ ssorted, int* __restrict__ dsorted, int E){
  int e = blockIdx.x * 256 + threadIdx.x;
  if (e >= E) return;
  int d = dst[e];
  int pos = atomicAdd(&cursor[d], 1);
  eperm[pos] = e;
  ssorted[pos] = src[e];
  dsorted[pos] = d;
}

// ghb[p][:] = bf16(gh[eperm[p]][:]) — all later gh access is sequential bf16
__global__ void convert_kernel(const float* __restrict__ gh, const int* __restrict__ eperm,
                               short* __restrict__ ghb, int E){
  int gid = blockIdx.x * 256 + threadIdx.x;
  int p = gid >> 4;
  if (p >= E) return;
  int q = gid & 15;
  int e = eperm[p];
  const float* gp = gh + (size_t)e*F + q*8;
  float4 x0 = *(const float4*)(gp);
  float4 x1 = *(const float4*)(gp + 4);
  s16x8 a;
  a[0]=f2bf(x0.x); a[1]=f2bf(x0.y); a[2]=f2bf(x0.z); a[3]=f2bf(x0.w);
  a[4]=f2bf(x1.x); a[5]=f2bf(x1.y); a[6]=f2bf(x1.z); a[7]=f2bf(x1.w);
  *(s16x8*)(ghb + (size_t)p*F + q*8) = a;
}

__global__ __launch_bounds__(256) void edge_gemm_sorted_kernel(
    const short* __restrict__ ghb, const short* __restrict__ Wt,
    const float* __restrict__ Psrc, const float* __restrict__ Pdst,
    const int* __restrict__ ssorted, const int* __restrict__ dsorted,
    const float* __restrict__ ba1, const float* __restrict__ Wa2, const float* __restrict__ ba2,
    float* __restrict__ av_s, int E)
{
  int tid = threadIdx.x;
  int wave = tid >> 6, lane = tid & 63;
  int lrow = lane & 15, lk8 = lane >> 4;

  s16x8 bfrag[2][4];
  float wa2v[2], ba1v[2];
  for (int cg = 0; cg < 2; ++cg){
    int col = wave*32 + cg*16 + lrow;
    wa2v[cg] = Wa2[col];
    ba1v[cg] = ba1[col];
    for (int kc = 0; kc < 4; ++kc)
      bfrag[cg][kc] = *(const s16x8*)(Wt + (size_t)col*F + kc*32 + lk8*8);
  }
  float ba2v = ba2[0];

  __shared__ float red[4][16][17];
  int ntiles = (E + 15) >> 4;
  for (int t = blockIdx.x; t < ntiles; t += gridDim.x){
    int p0 = t * 16;
    int arow = p0 + lrow; if (arow >= E) arow = E - 1;
    const short* gp = ghb + (size_t)arow*F;
    s16x8 afrag[4];
    for (int kc = 0; kc < 4; ++kc)
      afrag[kc] = *(const s16x8*)(gp + kc*32 + lk8*8);
    f32x4 acc0 = {0,0,0,0}, acc1 = {0,0,0,0};
    for (int kc = 0; kc < 4; ++kc){
      acc0 = __builtin_amdgcn_mfma_f32_16x16x32_bf16(afrag[kc], bfrag[0][kc], acc0, 0,0,0);
      acc1 = __builtin_amdgcn_mfma_f32_16x16x32_bf16(afrag[kc], bfrag[1][kc], acc1, 0,0,0);
    }
    float psum[4];
    for (int j = 0; j < 4; ++j){
      int p = p0 + lk8*4 + j;
      int pc = (p < E) ? p : E - 1;
      int s = ssorted[pc], d = dsorted[pc];
      int col0 = wave*32 + lrow, col1 = wave*32 + 16 + lrow;
      float h0 = acc0[j] + Psrc[(size_t)s*F + col0] + Pdst[(size_t)d*F + col0] + ba1v[0];
      float h1 = acc1[j] + Psrc[(size_t)s*F + col1] + Pdst[(size_t)d*F + col1] + ba1v[1];
      float ps = 0.0f;
      if (h0 > 0.0f) ps += h0 * wa2v[0];
      if (h1 > 0.0f) ps += h1 * wa2v[1];
      psum[j] = ps;
    }
    __syncthreads();
    for (int j = 0; j < 4; ++j) red[wave][lk8*4 + j][lrow] = psum[j];
    __syncthreads();
    int r = tid >> 4, c = tid & 15;
    float s2 = red[0][r][c] + red[1][r][c] + red[2][r][c] + red[3][r][c];
    s2 += __shfl_xor(s2, 1); s2 += __shfl_xor(s2, 2);
    s2 += __shfl_xor(s2, 4); s2 += __shfl_xor(s2, 8);
    if (c == 0 && p0 + r < E) av_s[p0 + r] = s2 + ba2v;
  }
}

// segmented softmax: one wave per dst node, contiguous av_s segment, no atomics
__global__ __launch_bounds__(256) void softmax_seg_kernel(
    const float* __restrict__ av_s, const int* __restrict__ off,
    float* __restrict__ alpha_s, int N)
{
  int lane = threadIdx.x & 63;
  int n = blockIdx.x * 4 + (threadIdx.x >> 6);
  if (n >= N) return;
  int start = off[n], end = off[n + 1];
  if (start >= end) return;
  float m = -3.0e38f;
  for (int idx = start + lane; idx < end; idx += 64)
    m = fmaxf(m, av_s[idx]);
  m = fmaxf(m, __shfl_xor(m, 1));  m = fmaxf(m, __shfl_xor(m, 2));
  m = fmaxf(m, __shfl_xor(m, 4));  m = fmaxf(m, __shfl_xor(m, 8));
  m = fmaxf(m, __shfl_xor(m, 16)); m = fmaxf(m, __shfl_xor(m, 32));
  float sum = 0.0f;
  for (int idx = start + lane; idx < end; idx += 64){
    float ex = expf(av_s[idx] - m);
    alpha_s[idx] = ex;
    sum += ex;
  }
  sum += __shfl_xor(sum, 1);  sum += __shfl_xor(sum, 2);
  sum += __shfl_xor(sum, 4);  sum += __shfl_xor(sum, 8);
  sum += __shfl_xor(sum, 16); sum += __shfl_xor(sum, 32);
  float r = 1.0f / sum;
  for (int idx = start + lane; idx < end; idx += 64)
    alpha_s[idx] *= r;
}

// gather + final: out[n] = epsp1[n] * sum_p(alpha_s[p]*ghb[p]*nf[ssorted[p]]) + nf[n]
__global__ __launch_bounds__(256) void gather_sorted_kernel(
    const short* __restrict__ ghb, const float* __restrict__ nf,
    const int* __restrict__ ssorted, const int* __restrict__ off,
    const float* __restrict__ alpha_s, const float* __restrict__ epsp1,
    float* __restrict__ out, int N)
{
  int lane = threadIdx.x & 63;
  int n = blockIdx.x * 4 + (threadIdx.x >> 6);
  if (n >= N) return;
  int start = off[n], end = off[n + 1];
  int c = lane * 2;
  float ax = 0.0f, ay = 0.0f;
  for (int base = start; base < end; base += 64){
    int idx = base + lane;
    int mysrc = 0; float mya = 0.0f;
    if (idx < end){
      mya = alpha_s[idx];
      mysrc = ssorted[idx];
    }
    int m = end - base; if (m > 64) m = 64;
    for (int it = 0; it < m; ++it){
      float alpha = __shfl(mya, it);
      int srow    = __shfl(mysrc, it);
      int p = base + it;
      unsigned gp = *(const unsigned*)(ghb + (size_t)p*F + c);
      float gx = bf2f((short)(gp & 0xffff));
      float gy = bf2f((short)(gp >> 16));
      float2 h = *(const float2*)(nf + (size_t)srow*F + c);
      ax += alpha * gx * h.x;
      ay += alpha * gy * h.y;
    }
  }
  float ep = epsp1[n];
  float2 x = *(const float2*)(nf + (size_t)n*F + c);
  float2 o;
  o.x = ep * ax + x.x;
  o.y = ep * ay + x.y;
  *(float2*)(out + (size_t)n*F + c) = o;
}

// =================== fallback-path kernels (round-4, proven) ===================

__global__ void init_kernel(unsigned* __restrict__ amax, float* __restrict__ denom,
                            int* __restrict__ cnt, int N){
  int i = blockIdx.x * 256 + threadIdx.x;
  if (i < N){ amax[i] = 0x007FFFFFu; denom[i] = 0.0f; cnt[i] = 0; }
}

__global__ __launch_bounds__(256) void edge_gemm_kernel(
    const float* __restrict__ gh, const short* __restrict__ Wt,
    const float* __restrict__ Psrc, const float* __restrict__ Pdst,
    const int* __restrict__ src, const int* __restrict__ dst,
    const float* __restrict__ ba1, const float* __restrict__ Wa2, const float* __restrict__ ba2,
    float* __restrict__ av, int E)
{
  int tid = threadIdx.x;
  int wave = tid >> 6, lane = tid & 63;
  int lrow = lane & 15, lk8 = lane >> 4;

  s16x8 bfrag[2][4];
  float wa2v[2], ba1v[2];
  for (int cg = 0; cg < 2; ++cg){
    int col = wave*32 + cg*16 + lrow;
    wa2v[cg] = Wa2[col];
    ba1v[cg] = ba1[col];
    for (int kc = 0; kc < 4; ++kc)
      bfrag[cg][kc] = *(const s16x8*)(Wt + (size_t)col*F + kc*32 + lk8*8);
  }
  float ba2v = ba2[0];

  __shared__ float red[4][16][17];
  int ntiles = (E + 15) >> 4;
  for (int t = blockIdx.x; t < ntiles; t += gridDim.x){
    int e0 = t * 16;
    int arow = e0 + lrow; if (arow >= E) arow = E - 1;
    const float* gp = gh + (size_t)arow*F;
    s16x8 afrag[4];
    for (int kc = 0; kc < 4; ++kc){
      float4 x0 = *(const float4*)(gp + kc*32 + lk8*8);
      float4 x1 = *(const float4*)(gp + kc*32 + lk8*8 + 4);
      s16x8 a;
      a[0]=f2bf(x0.x); a[1]=f2bf(x0.y); a[2]=f2bf(x0.z); a[3]=f2bf(x0.w);
      a[4]=f2bf(x1.x); a[5]=f2bf(x1.y); a[6]=f2bf(x1.z); a[7]=f2bf(x1.w);
      afrag[kc] = a;
    }
    f32x4 acc0 = {0,0,0,0}, acc1 = {0,0,0,0};
    for (int kc = 0; kc < 4; ++kc){
      acc0 = __builtin_amdgcn_mfma_f32_16x16x32_bf16(afrag[kc], bfrag[0][kc], acc0, 0,0,0);
      acc1 = __builtin_amdgcn_mfma_f32_16x16x32_bf16(afrag[kc], bfrag[1][kc], acc1, 0,0,0);
    }
    float psum[4];
    for (int j = 0; j < 4; ++j){
      int e = e0 + lk8*4 + j;
      int ec = (e < E) ? e : E - 1;
      int s = src[ec], d = dst[ec];
      int col0 = wave*32 + lrow, col1 = wave*32 + 16 + lrow;
      float h0 = acc0[j] + Psrc[(size_t)s*F + col0] + Pdst[(size_t)d*F + col0] + ba1v[0];
      float h1 = acc1[j] + Psrc[(size_t)s*F + col1] + Pdst[(size_t)d*F + col1] + ba1v[1];
      float ps = 0.0f;
      if (h0 > 0.0f) ps += h0 * wa2v[0];
      if (h1 > 0.0f) ps += h1 * wa2v[1];
      psum[j] = ps;
    }
    __syncthreads();
    for (int j = 0; j < 4; ++j) red[wave][lk8*4 + j][lrow] = psum[j];
    __syncthreads();
    int r = tid >> 4, c = tid & 15;
    float s2 = red[0][r][c] + red[1][r][c] + red[2][r][c] + red[3][r][c];
    s2 += __shfl_xor(s2, 1); s2 += __shfl_xor(s2, 2);
    s2 += __shfl_xor(s2, 4); s2 += __shfl_xor(s2, 8);
    if (c == 0 && e0 + r < E) av[e0 + r] = s2 + ba2v;
  }
}

__global__ void amax_count_kernel(const float* __restrict__ av, const int* __restrict__ dst,
                                  unsigned* __restrict__ amax, int* __restrict__ cnt, int E){
  int e = blockIdx.x * 256 + threadIdx.x;
  if (e >= E) return;
  int d = dst[e];
  atomicMax(&amax[d], fenc(av[e]));
  atomicAdd(&cnt[d], 1);
}

__global__ void exden_fill_kernel(const float* __restrict__ av, const int* __restrict__ dst,
                                  const unsigned* __restrict__ amax,
                                  float* __restrict__ exv, float* __restrict__ denom,
                                  int* __restrict__ cursor, int* __restrict__ perm, int E){
  int e = blockIdx.x * 256 + threadIdx.x;
  if (e >= E) return;
  int d = dst[e];
  float ex = expf(av[e] - fdec(amax[d]));
  exv[e] = ex;
  atomicAdd(&denom[d], ex);
  int pos = atomicAdd(&cursor[d], 1);
  perm[pos] = e;
}

__global__ __launch_bounds__(256) void gather_kernel(
    const float* __restrict__ gh, const float* __restrict__ nf,
    const int* __restrict__ src, const int* __restrict__ perm, const int* __restrict__ off,
    const float* __restrict__ exv, const float* __restrict__ denom,
    const float* __restrict__ epsp1, float* __restrict__ out, int N)
{
  int lane = threadIdx.x & 63;
  int n = blockIdx.x * 4 + (threadIdx.x >> 6);
  if (n >= N) return;
  int start = off[n], end = off[n + 1];
  float rden = 1.0f / denom[n];
  int c = lane * 2;
  float ax = 0.0f, ay = 0.0f;
  for (int base = start; base < end; base += 64){
    int idx = base + lane;
    int mye = 0, mysrc = 0; float mya = 0.0f;
    if (idx < end){
      mye = perm[idx];
      mysrc = src[mye];
      mya = exv[mye] * rden;
    }
    int m = end - base; if (m > 64) m = 64;
    for (int it = 0; it < m; ++it){
      float alpha = __shfl(mya, it);
      int e     = __shfl(mye, it);
      int srow  = __shfl(mysrc, it);
      float2 g = *(const float2*)(gh + (size_t)e*F + c);
      float2 h = *(const float2*)(nf + (size_t)srow*F + c);
      ax += alpha * g.x * h.x;
      ay += alpha * g.y * h.y;
    }
  }
  float ep = epsp1[n];
  float2 x = *(const float2*)(nf + (size_t)n*F + c);
  float2 o;
  o.x = ep * ax + x.x;
  o.y = ep * ay + x.y;
  *(float2*)(out + (size_t)n*F + c) = o;
}

// =================== launch ===================

extern "C" void kernel_launch(void* const* d_in, const int* in_sizes, int n_in,
                              void* d_out, int out_size, void* d_ws, size_t ws_size,
                              hipStream_t stream)
{
  const float* nf  = (const float*)d_in[0];
  const float* gh  = (const float*)d_in[1];
  const int*   src = (const int*)d_in[2];
  const int*   dst = (const int*)d_in[3];
  const float* Wa1 = (const float*)d_in[4];
  const float* ba1 = (const float*)d_in[5];
  const float* Wa2 = (const float*)d_in[6];
  const float* ba2 = (const float*)d_in[7];
  const float* We1 = (const float*)d_in[8];
  const float* be1 = (const float*)d_in[9];
  const float* We2 = (const float*)d_in[10];
  const float* be2 = (const float*)d_in[11];
  int N = in_sizes[0] / F;
  int E = in_sizes[2];
  float* out = (float*)d_out;

  char* base = (char*)d_ws;
  char* w = base;
  auto alloc = [&](size_t bytes) -> char* {
    char* p = w; w += (bytes + 255) & ~(size_t)255; return p;
  };

  // ---- sorted-path layout ----
  short*    packW   = (short*)alloc((size_t)4*F*F*sizeof(short));
  float*    Psrc    = (float*)alloc((size_t)N*F*sizeof(float));
  float*    Pdst    = (float*)alloc((size_t)N*F*sizeof(float));
  float*    epsp1   = (float*)alloc((size_t)N*sizeof(float));
  int*      cnt     = (int*)  alloc((size_t)N*sizeof(int));
  int*      off     = (int*)  alloc((size_t)(N+1)*sizeof(int));
  int*      cursor  = (int*)  alloc((size_t)N*sizeof(int));
  int*      eperm   = (int*)  alloc((size_t)E*sizeof(int));
  int*      ssorted = (int*)  alloc((size_t)E*sizeof(int));
  int*      dsorted = (int*)  alloc((size_t)E*sizeof(int));
  float*    av_s    = (float*)alloc((size_t)E*sizeof(float));
  float*    alpha_s = (float*)alloc((size_t)E*sizeof(float));
  short*    ghb     = (short*)alloc((size_t)E*F*sizeof(short));
  size_t sorted_need = (size_t)(w - base);

  if (ws_size >= sorted_need){
    initc_kernel<<<(N + 255)/256, 256, 0, stream>>>(cnt, N);
    count_kernel<<<(E + 255)/256, 256, 0, stream>>>(dst, cnt, E);
    scan_kernel<<<1, 256, 0, stream>>>(cnt, off, cursor, N);
    fill_sorted_kernel<<<(E + 255)/256, 256, 0, stream>>>(src, dst, cursor,
                                                          eperm, ssorted, dsorted, E);
    convert_kernel<<<((size_t)E*16 + 255)/256, 256, 0, stream>>>(gh, eperm, ghb, E);
    pack_kernel<<<dim3(F, 4), F, 0, stream>>>(Wa1, We1, packW);
    node_gemm_kernel<<<dim3(512, 3), 256, 0, stream>>>(nf, packW, Psrc, Pdst, epsp1,
                                                       be1, We2, be2, N);
    edge_gemm_sorted_kernel<<<2048, 256, 0, stream>>>(ghb, packW + (size_t)2*F*F,
                                                      Psrc, Pdst, ssorted, dsorted,
                                                      ba1, Wa2, ba2, av_s, E);
    softmax_seg_kernel<<<(N + 3)/4, 256, 0, stream>>>(av_s, off, alpha_s, N);
    gather_sorted_kernel<<<(N + 3)/4, 256, 0, stream>>>(ghb, nf, ssorted, off,
                                                        alpha_s, epsp1, out, N);
  } else {
    // ---- fallback: round-4 proven path (~33 MB) ----
    w = base;
    short*    packW2  = (short*)   alloc((size_t)4*F*F*sizeof(short));
    float*    Psrc2   = (float*)   alloc((size_t)N*F*sizeof(float));
    float*    Pdst2   = (float*)   alloc((size_t)N*F*sizeof(float));
    float*    epsp12  = (float*)   alloc((size_t)N*sizeof(float));
    float*    av      = (float*)   alloc((size_t)E*sizeof(float));
    float*    exv     = (float*)   alloc((size_t)E*sizeof(float));
    unsigned* amax    = (unsigned*)alloc((size_t)N*sizeof(unsigned));
    float*    denom   = (float*)   alloc((size_t)N*sizeof(float));
    int*      cnt2    = (int*)     alloc((size_t)N*sizeof(int));
    int*      off2    = (int*)     alloc((size_t)(N+1)*sizeof(int));
    int*      cursor2 = (int*)     alloc((size_t)N*sizeof(int));
    int*      perm    = (int*)     alloc((size_t)E*sizeof(int));

    init_kernel<<<(N + 255)/256, 256, 0, stream>>>(amax, denom, cnt2, N);
    pack_kernel<<<dim3(F, 4), F, 0, stream>>>(Wa1, We1, packW2);
    node_gemm_kernel<<<dim3(512, 3), 256, 0, stream>>>(nf, packW2, Psrc2, Pdst2, epsp12,
                                                       be1, We2, be2, N);
    edge_gemm_kernel<<<2048, 256, 0, stream>>>(gh, packW2 + (size_t)2*F*F, Psrc2, Pdst2,
                                               src, dst, ba1, Wa2, ba2, av, E);
    amax_count_kernel<<<(E + 255)/256, 256, 0, stream>>>(av, dst, amax, cnt2, E);
    scan_kernel<<<1, 256, 0, stream>>>(cnt2, off2, cursor2, N);
    exden_fill_kernel<<<(E + 255)/256, 256, 0, stream>>>(av, dst, amax, exv, denom,
                                                         cursor2, perm, E);
    gather_kernel<<<(N + 3)/4, 256, 0, stream>>>(gh, nf, src, perm, off2,
                                                 exv, denom, epsp12, out, N);
  }
}

// Round 6
// 628.168 us; speedup vs baseline: 1.8090x; 1.0460x over previous
//
#include <hip/hip_runtime.h>

#define F 128

typedef short s16x8 __attribute__((ext_vector_type(8)));
typedef float f32x4 __attribute__((ext_vector_type(4)));

__device__ __forceinline__ short f2bf(float f){
  unsigned u = __float_as_uint(f);
  u = u + 0x7FFFu + ((u >> 16) & 1u);   // round-to-nearest-even
  return (short)(u >> 16);
}
__device__ __forceinline__ float bf2f(short s){
  return __uint_as_float(((unsigned)(unsigned short)s) << 16);
}

// ---------------- pack weights: packW[g][col][k] = bf16(W_g[k][col]) ----------------
__global__ void pack_kernel(const float* __restrict__ Wa1, const float* __restrict__ We1,
                            short* __restrict__ packW){
  int col = blockIdx.x, g = blockIdx.y, k = threadIdx.x;
  float v;
  if      (g == 0) v = Wa1[k*F + col];
  else if (g == 1) v = Wa1[(F + k)*F + col];
  else if (g == 2) v = Wa1[(2*F + k)*F + col];
  else             v = We1[k*F + col];
  packW[((size_t)g*F + col)*F + k] = f2bf(v);
}

// ---------------- node GEMM: Psrc, Pdst, epsp1 ----------------
__global__ __launch_bounds__(256) void node_gemm_kernel(
    const float* __restrict__ nf, const short* __restrict__ packW,
    float* __restrict__ Psrc, float* __restrict__ Pdst, float* __restrict__ epsp1,
    const float* __restrict__ be1, const float* __restrict__ We2, const float* __restrict__ be2,
    int N)
{
  int g = blockIdx.y;                 // 0: src-proj, 1: dst-proj, 2: We1 path
  int m = (g == 2) ? 3 : g;
  int tid = threadIdx.x;
  int wave = tid >> 6, lane = tid & 63;
  int lrow = lane & 15, lk8 = lane >> 4;

  const short* W = packW + (size_t)m*F*F;
  s16x8 bfrag[2][4];
  float we2v[2], be1v[2];
  for (int cg = 0; cg < 2; ++cg){
    int col = wave*32 + cg*16 + lrow;
    for (int kc = 0; kc < 4; ++kc)
      bfrag[cg][kc] = *(const s16x8*)(W + (size_t)col*F + kc*32 + lk8*8);
    if (g == 2){ we2v[cg] = We2[col]; be1v[cg] = be1[col]; }
  }
  float be2v = (g == 2) ? be2[0] : 0.0f;

  __shared__ float red[4][16][17];
  int ntiles = (N + 15) >> 4;
  for (int t = blockIdx.x; t < ntiles; t += gridDim.x){
    int n0 = t * 16;
    int arow = n0 + lrow; if (arow >= N) arow = N - 1;
    const float* ap = nf + (size_t)arow*F;
    s16x8 afrag[4];
    for (int kc = 0; kc < 4; ++kc){
      float4 x0 = *(const float4*)(ap + kc*32 + lk8*8);
      float4 x1 = *(const float4*)(ap + kc*32 + lk8*8 + 4);
      s16x8 a;
      a[0]=f2bf(x0.x); a[1]=f2bf(x0.y); a[2]=f2bf(x0.z); a[3]=f2bf(x0.w);
      a[4]=f2bf(x1.x); a[5]=f2bf(x1.y); a[6]=f2bf(x1.z); a[7]=f2bf(x1.w);
      afrag[kc] = a;
    }
    f32x4 acc0 = {0,0,0,0}, acc1 = {0,0,0,0};
    for (int kc = 0; kc < 4; ++kc){
      acc0 = __builtin_amdgcn_mfma_f32_16x16x32_bf16(afrag[kc], bfrag[0][kc], acc0, 0,0,0);
      acc1 = __builtin_amdgcn_mfma_f32_16x16x32_bf16(afrag[kc], bfrag[1][kc], acc1, 0,0,0);
    }
    if (g < 2){
      float* P = (g == 0) ? Psrc : Pdst;
      for (int j = 0; j < 4; ++j){
        int n = n0 + lk8*4 + j;
        if (n < N){
          P[(size_t)n*F + wave*32 + lrow]      = acc0[j];
          P[(size_t)n*F + wave*32 + 16 + lrow] = acc1[j];
        }
      }
    } else {
      float psum[4];
      for (int j = 0; j < 4; ++j){
        float h0 = acc0[j] + be1v[0];
        float h1 = acc1[j] + be1v[1];
        float s = 0.0f;
        if (h0 > 0.0f) s += h0 * we2v[0];
        if (h1 > 0.0f) s += h1 * we2v[1];
        psum[j] = s;
      }
      __syncthreads();
      for (int j = 0; j < 4; ++j) red[wave][lk8*4 + j][lrow] = psum[j];
      __syncthreads();
      int r = tid >> 4, c = tid & 15;
      float s2 = red[0][r][c] + red[1][r][c] + red[2][r][c] + red[3][r][c];
      s2 += __shfl_xor(s2, 1); s2 += __shfl_xor(s2, 2);
      s2 += __shfl_xor(s2, 4); s2 += __shfl_xor(s2, 8);
      if (c == 0 && n0 + r < N) epsp1[n0 + r] = 1.0f + s2 + be2v;
    }
  }
}

// ---------------- sort building ----------------
__global__ void initc_kernel(int* __restrict__ cnt, int N){
  int i = blockIdx.x * 256 + threadIdx.x;
  if (i < N) cnt[i] = 0;
}

__global__ void count_kernel(const int* __restrict__ dst, int* __restrict__ cnt, int E){
  int e = blockIdx.x * 256 + threadIdx.x;
  if (e < E) atomicAdd(&cnt[dst[e]], 1);
}

__global__ void scan_kernel(const int* __restrict__ cnt, int* __restrict__ off,
                            int* __restrict__ cursor, int N){
  __shared__ int tmp[256];
  __shared__ int carry;
  if (threadIdx.x == 0) carry = 0;
  __syncthreads();
  for (int base = 0; base < N; base += 256){
    int i = base + threadIdx.x;
    int v = (i < N) ? cnt[i] : 0;
    tmp[threadIdx.x] = v;
    for (int s = 1; s < 256; s <<= 1){
      __syncthreads();
      int t = (threadIdx.x >= s) ? tmp[threadIdx.x - s] : 0;
      __syncthreads();
      tmp[threadIdx.x] += t;
    }
    __syncthreads();
    int incl = tmp[threadIdx.x];
    int myoff = carry + incl - v;          // exclusive
    if (i < N){ off[i] = myoff; cursor[i] = myoff; }
    __syncthreads();
    if (threadIdx.x == 255) carry += tmp[255];
    __syncthreads();
  }
  if (threadIdx.x == 0) off[N] = carry;
}

__global__ void fill_sorted_kernel(const int* __restrict__ src, const int* __restrict__ dst,
                                   int* __restrict__ cursor, int* __restrict__ eperm,
                                   int* __restrict__ ssorted, int* __restrict__ dsorted, int E){
  int e = blockIdx.x * 256 + threadIdx.x;
  if (e >= E) return;
  int d = dst[e];
  int pos = atomicAdd(&cursor[d], 1);
  eperm[pos] = e;
  ssorted[pos] = src[e];
  dsorted[pos] = d;
}

// ghb[p][:] = bf16(gh[eperm[p]][:])
__global__ void convert_kernel(const float* __restrict__ gh, const int* __restrict__ eperm,
                               short* __restrict__ ghb, int E){
  int gid = blockIdx.x * 256 + threadIdx.x;
  int p = gid >> 4;
  if (p >= E) return;
  int q = gid & 15;
  int e = eperm[p];
  const float* gp = gh + (size_t)e*F + q*8;
  float4 x0 = *(const float4*)(gp);
  float4 x1 = *(const float4*)(gp + 4);
  s16x8 a;
  a[0]=f2bf(x0.x); a[1]=f2bf(x0.y); a[2]=f2bf(x0.z); a[3]=f2bf(x0.w);
  a[4]=f2bf(x1.x); a[5]=f2bf(x1.y); a[6]=f2bf(x1.z); a[7]=f2bf(x1.w);
  *(s16x8*)(ghb + (size_t)p*F + q*8) = a;
}

// ---------------- edge GEMM v2: wave-owned tiles, no main-loop barriers ----------------
// ex_s[p] = exp( relu(ghb[p]@W + Psrc[s] + Pdst[d] + ba1) . Wa2 + ba2 )
__global__ __launch_bounds__(256) void edge_gemm2_kernel(
    const short* __restrict__ ghb, const short* __restrict__ Wt,
    const float* __restrict__ Psrc, const float* __restrict__ Pdst,
    const int* __restrict__ ssorted, const int* __restrict__ dsorted,
    const float* __restrict__ ba1, const float* __restrict__ Wa2, const float* __restrict__ ba2,
    float* __restrict__ ex_s, int E)
{
  __shared__ short wlds[F*F];          // 32 KB, XOR-swizzled
  int tid = threadIdx.x;
  for (int i = tid; i < F*16; i += 256){
    int row = i >> 4, o16 = i & 15;    // row = output col, o16 = 16B chunk along k
    s16x8 v = *(const s16x8*)(Wt + (size_t)row*F + o16*8);
    *(s16x8*)((char*)wlds + row*256 + ((o16*16) ^ ((row & 7) << 4))) = v;
  }
  __syncthreads();

  int wave = tid >> 6, lane = tid & 63;
  int lrow = lane & 15, lk8 = lane >> 4;
  int sw = (lrow & 7) << 4;            // swizzle term (col&7 == lrow&7)

  float wa2v[8], ba1v[8];
#pragma unroll
  for (int cg = 0; cg < 8; ++cg){
    wa2v[cg] = Wa2[cg*16 + lrow];
    ba1v[cg] = ba1[cg*16 + lrow];
  }
  float ba2v = ba2[0];

  int ntiles = (E + 15) >> 4;
  int gw = blockIdx.x * 4 + wave, nw = gridDim.x * 4;
  for (int t = gw; t < ntiles; t += nw){
    int p0 = t * 16;
    int ar = p0 + lrow; if (ar >= E) ar = E - 1;
    const short* gp = ghb + (size_t)ar*F;
    s16x8 a0 = *(const s16x8*)(gp +  0 + lk8*8);
    s16x8 a1 = *(const s16x8*)(gp + 32 + lk8*8);
    s16x8 a2 = *(const s16x8*)(gp + 64 + lk8*8);
    s16x8 a3 = *(const s16x8*)(gp + 96 + lk8*8);

    int sIdx[4], dIdx[4];
#pragma unroll
    for (int j = 0; j < 4; ++j){
      int p = p0 + lk8*4 + j; int pc = (p < E) ? p : E - 1;
      sIdx[j] = ssorted[pc]; dIdx[j] = dsorted[pc];
    }

    float colsum[4] = {0.f, 0.f, 0.f, 0.f};
#pragma unroll
    for (int cg = 0; cg < 8; cg += 2){
      float ps0[4], pd0[4], ps1[4], pd1[4];
#pragma unroll
      for (int j = 0; j < 4; ++j){
        ps0[j] = Psrc[(size_t)sIdx[j]*F +  cg   *16 + lrow];
        pd0[j] = Pdst[(size_t)dIdx[j]*F +  cg   *16 + lrow];
        ps1[j] = Psrc[(size_t)sIdx[j]*F + (cg+1)*16 + lrow];
        pd1[j] = Pdst[(size_t)dIdx[j]*F + (cg+1)*16 + lrow];
      }
      int col0 = cg*16 + lrow, col1 = col0 + 16;
      const char* wb0 = (const char*)wlds + col0*256;
      const char* wb1 = (const char*)wlds + col1*256;
      s16x8 b0 = *(const s16x8*)(wb0 + ((  0 + lk8*16) ^ sw));
      s16x8 b1 = *(const s16x8*)(wb0 + (( 64 + lk8*16) ^ sw));
      s16x8 b2 = *(const s16x8*)(wb0 + ((128 + lk8*16) ^ sw));
      s16x8 b3 = *(const s16x8*)(wb0 + ((192 + lk8*16) ^ sw));
      s16x8 c0 = *(const s16x8*)(wb1 + ((  0 + lk8*16) ^ sw));
      s16x8 c1 = *(const s16x8*)(wb1 + (( 64 + lk8*16) ^ sw));
      s16x8 c2 = *(const s16x8*)(wb1 + ((128 + lk8*16) ^ sw));
      s16x8 c3 = *(const s16x8*)(wb1 + ((192 + lk8*16) ^ sw));
      f32x4 accA = {0,0,0,0}, accB = {0,0,0,0};
      accA = __builtin_amdgcn_mfma_f32_16x16x32_bf16(a0, b0, accA, 0,0,0);
      accB = __builtin_amdgcn_mfma_f32_16x16x32_bf16(a0, c0, accB, 0,0,0);
      accA = __builtin_amdgcn_mfma_f32_16x16x32_bf16(a1, b1, accA, 0,0,0);
      accB = __builtin_amdgcn_mfma_f32_16x16x32_bf16(a1, c1, accB, 0,0,0);
      accA = __builtin_amdgcn_mfma_f32_16x16x32_bf16(a2, b2, accA, 0,0,0);
      accB = __builtin_amdgcn_mfma_f32_16x16x32_bf16(a2, c2, accB, 0,0,0);
      accA = __builtin_amdgcn_mfma_f32_16x16x32_bf16(a3, b3, accA, 0,0,0);
      accB = __builtin_amdgcn_mfma_f32_16x16x32_bf16(a3, c3, accB, 0,0,0);
#pragma unroll
      for (int j = 0; j < 4; ++j){
        float h0 = accA[j] + ps0[j] + pd0[j] + ba1v[cg];
        if (h0 > 0.0f) colsum[j] += h0 * wa2v[cg];
        float h1 = accB[j] + ps1[j] + pd1[j] + ba1v[cg+1];
        if (h1 > 0.0f) colsum[j] += h1 * wa2v[cg+1];
      }
    }
#pragma unroll
    for (int j = 0; j < 4; ++j){
      float s = colsum[j];
      s += __shfl_xor(s, 1); s += __shfl_xor(s, 2);
      s += __shfl_xor(s, 4); s += __shfl_xor(s, 8);
      colsum[j] = s;
    }
    if (lrow == 0){
#pragma unroll
      for (int j = 0; j < 4; ++j){
        int p = p0 + lk8*4 + j;
        if (p < E){
          float aval = fminf(colsum[j] + ba2v, 80.0f);  // softmax is shift-invariant; a ~ N(0,~0.5)
          ex_s[p] = __expf(aval);
        }
      }
    }
  }
}

// ---------------- gather + denom + final ----------------
__global__ __launch_bounds__(256) void gather_final_kernel(
    const short* __restrict__ ghb, const float* __restrict__ nf,
    const int* __restrict__ ssorted, const int* __restrict__ off,
    const float* __restrict__ ex_s, const float* __restrict__ epsp1,
    float* __restrict__ out, int N)
{
  int lane = threadIdx.x & 63;
  int n = blockIdx.x * 4 + (threadIdx.x >> 6);
  if (n >= N) return;
  int start = off[n], end = off[n + 1];

  float sum = 0.0f;
  for (int idx = start + lane; idx < end; idx += 64) sum += ex_s[idx];
  sum += __shfl_xor(sum, 1);  sum += __shfl_xor(sum, 2);
  sum += __shfl_xor(sum, 4);  sum += __shfl_xor(sum, 8);
  sum += __shfl_xor(sum, 16); sum += __shfl_xor(sum, 32);
  float rden = 1.0f / sum;    // deg==0 -> inf, never used (loop body skipped)

  int c = lane * 2;
  float ax = 0.0f, ay = 0.0f;
  for (int base = start; base < end; base += 64){
    int idx = base + lane;
    int mysrc = 0; float myal = 0.0f;
    if (idx < end){
      myal = ex_s[idx] * rden;
      mysrc = ssorted[idx];
    }
    int m = end - base; if (m > 64) m = 64;
    for (int it = 0; it < m; ++it){
      float alpha = __shfl(myal, it);
      int srow    = __shfl(mysrc, it);
      int p = base + it;
      unsigned gpv = *(const unsigned*)(ghb + (size_t)p*F + c);
      float gx = bf2f((short)(gpv & 0xffff));
      float gy = bf2f((short)(gpv >> 16));
      float2 h = *(const float2*)(nf + (size_t)srow*F + c);
      ax += alpha * gx * h.x;
      ay += alpha * gy * h.y;
    }
  }
  float ep = epsp1[n];
  float2 x = *(const float2*)(nf + (size_t)n*F + c);
  float2 o;
  o.x = ep * ax + x.x;
  o.y = ep * ay + x.y;
  *(float2*)(out + (size_t)n*F + c) = o;
}

// =================== launch ===================

extern "C" void kernel_launch(void* const* d_in, const int* in_sizes, int n_in,
                              void* d_out, int out_size, void* d_ws, size_t ws_size,
                              hipStream_t stream)
{
  const float* nf  = (const float*)d_in[0];
  const float* gh  = (const float*)d_in[1];
  const int*   src = (const int*)d_in[2];
  const int*   dst = (const int*)d_in[3];
  const float* Wa1 = (const float*)d_in[4];
  const float* ba1 = (const float*)d_in[5];
  const float* Wa2 = (const float*)d_in[6];
  const float* ba2 = (const float*)d_in[7];
  const float* We1 = (const float*)d_in[8];
  const float* be1 = (const float*)d_in[9];
  const float* We2 = (const float*)d_in[10];
  const float* be2 = (const float*)d_in[11];
  int N = in_sizes[0] / F;
  int E = in_sizes[2];
  float* out = (float*)d_out;

  char* w = (char*)d_ws;
  auto alloc = [&](size_t bytes) -> char* {
    char* p = w; w += (bytes + 255) & ~(size_t)255; return p;
  };
  short* packW   = (short*)alloc((size_t)4*F*F*sizeof(short));
  float* Psrc    = (float*)alloc((size_t)N*F*sizeof(float));
  float* Pdst    = (float*)alloc((size_t)N*F*sizeof(float));
  float* epsp1   = (float*)alloc((size_t)N*sizeof(float));
  int*   cnt     = (int*)  alloc((size_t)N*sizeof(int));
  int*   off     = (int*)  alloc((size_t)(N+1)*sizeof(int));
  int*   cursor  = (int*)  alloc((size_t)N*sizeof(int));
  int*   eperm   = (int*)  alloc((size_t)E*sizeof(int));
  int*   ssorted = (int*)  alloc((size_t)E*sizeof(int));
  int*   dsorted = (int*)  alloc((size_t)E*sizeof(int));
  float* ex_s    = (float*)alloc((size_t)E*sizeof(float));
  short* ghb     = (short*)alloc((size_t)E*F*sizeof(short));

  initc_kernel<<<(N + 255)/256, 256, 0, stream>>>(cnt, N);
  count_kernel<<<(E + 255)/256, 256, 0, stream>>>(dst, cnt, E);
  scan_kernel<<<1, 256, 0, stream>>>(cnt, off, cursor, N);
  fill_sorted_kernel<<<(E + 255)/256, 256, 0, stream>>>(src, dst, cursor,
                                                        eperm, ssorted, dsorted, E);
  convert_kernel<<<((size_t)E*16 + 255)/256, 256, 0, stream>>>(gh, eperm, ghb, E);
  pack_kernel<<<dim3(F, 4), F, 0, stream>>>(Wa1, We1, packW);
  node_gemm_kernel<<<dim3(512, 3), 256, 0, stream>>>(nf, packW, Psrc, Pdst, epsp1,
                                                     be1, We2, be2, N);
  edge_gemm2_kernel<<<2048, 256, 0, stream>>>(ghb, packW + (size_t)2*F*F,
                                              Psrc, Pdst, ssorted, dsorted,
                                              ba1, Wa2, ba2, ex_s, E);
  gather_final_kernel<<<(N + 3)/4, 256, 0, stream>>>(ghb, nf, ssorted, off,
                                                     ex_s, epsp1, out, N);
}

// Round 7
// 470.001 us; speedup vs baseline: 2.4177x; 1.3365x over previous
//
#include <hip/hip_runtime.h>

#define F 128

typedef short s16x8 __attribute__((ext_vector_type(8)));
typedef float f32x4 __attribute__((ext_vector_type(4)));

__device__ __forceinline__ short f2bf(float f){
  unsigned u = __float_as_uint(f);
  u = u + 0x7FFFu + ((u >> 16) & 1u);   // round-to-nearest-even
  return (short)(u >> 16);
}

// ---------------- pack weights: packW[g][col][k] = bf16(W_g[k][col]) ----------------
__global__ void pack_kernel(const float* __restrict__ Wa1, const float* __restrict__ We1,
                            short* __restrict__ packW){
  int col = blockIdx.x, g = blockIdx.y, k = threadIdx.x;
  float v;
  if      (g == 0) v = Wa1[k*F + col];
  else if (g == 1) v = Wa1[(F + k)*F + col];
  else if (g == 2) v = Wa1[(2*F + k)*F + col];
  else             v = We1[k*F + col];
  packW[((size_t)g*F + col)*F + k] = f2bf(v);
}

// ---------------- fused node GEMM: one pass over nf -> Psrc, Pdst, epsp1 ----------------
__global__ __launch_bounds__(256) void node_gemm_kernel(
    const float* __restrict__ nf, const short* __restrict__ packW,
    float* __restrict__ Psrc, float* __restrict__ Pdst, float* __restrict__ epsp1,
    const float* __restrict__ be1, const float* __restrict__ We2, const float* __restrict__ be2,
    int N)
{
  int tid = threadIdx.x;
  int wave = tid >> 6, lane = tid & 63;
  int lrow = lane & 15, lk8 = lane >> 4;

  s16x8 bfrag[3][2][4];               // m = Wa1-src, Wa1-dst, We1
#pragma unroll
  for (int mi = 0; mi < 3; ++mi){
    int m = (mi == 2) ? 3 : mi;
    const short* W = packW + (size_t)m*F*F;
#pragma unroll
    for (int cg = 0; cg < 2; ++cg){
      int col = wave*32 + cg*16 + lrow;
#pragma unroll
      for (int kc = 0; kc < 4; ++kc)
        bfrag[mi][cg][kc] = *(const s16x8*)(W + (size_t)col*F + kc*32 + lk8*8);
    }
  }
  float we2v[2], be1v[2];
#pragma unroll
  for (int cg = 0; cg < 2; ++cg){
    int col = wave*32 + cg*16 + lrow;
    we2v[cg] = We2[col];
    be1v[cg] = be1[col];
  }
  float be2v = be2[0];

  __shared__ float red[4][16][17];
  int ntiles = (N + 15) >> 4;
  for (int t = blockIdx.x; t < ntiles; t += gridDim.x){
    int n0 = t * 16;
    int arow = n0 + lrow; if (arow >= N) arow = N - 1;
    const float* ap = nf + (size_t)arow*F;
    s16x8 afrag[4];
#pragma unroll
    for (int kc = 0; kc < 4; ++kc){
      float4 x0 = *(const float4*)(ap + kc*32 + lk8*8);
      float4 x1 = *(const float4*)(ap + kc*32 + lk8*8 + 4);
      s16x8 a;
      a[0]=f2bf(x0.x); a[1]=f2bf(x0.y); a[2]=f2bf(x0.z); a[3]=f2bf(x0.w);
      a[4]=f2bf(x1.x); a[5]=f2bf(x1.y); a[6]=f2bf(x1.z); a[7]=f2bf(x1.w);
      afrag[kc] = a;
    }
    f32x4 acc[3][2];
#pragma unroll
    for (int mi = 0; mi < 3; ++mi)
#pragma unroll
      for (int cg = 0; cg < 2; ++cg)
        acc[mi][cg] = (f32x4){0,0,0,0};
#pragma unroll
    for (int kc = 0; kc < 4; ++kc){
#pragma unroll
      for (int mi = 0; mi < 3; ++mi){
        acc[mi][0] = __builtin_amdgcn_mfma_f32_16x16x32_bf16(afrag[kc], bfrag[mi][0][kc], acc[mi][0], 0,0,0);
        acc[mi][1] = __builtin_amdgcn_mfma_f32_16x16x32_bf16(afrag[kc], bfrag[mi][1][kc], acc[mi][1], 0,0,0);
      }
    }
#pragma unroll
    for (int j = 0; j < 4; ++j){
      int n = n0 + lk8*4 + j;
      if (n < N){
        Psrc[(size_t)n*F + wave*32 + lrow]      = acc[0][0][j];
        Psrc[(size_t)n*F + wave*32 + 16 + lrow] = acc[0][1][j];
        Pdst[(size_t)n*F + wave*32 + lrow]      = acc[1][0][j];
        Pdst[(size_t)n*F + wave*32 + 16 + lrow] = acc[1][1][j];
      }
    }
    float psum[4];
#pragma unroll
    for (int j = 0; j < 4; ++j){
      float h0 = acc[2][0][j] + be1v[0];
      float h1 = acc[2][1][j] + be1v[1];
      float s = 0.0f;
      if (h0 > 0.0f) s += h0 * we2v[0];
      if (h1 > 0.0f) s += h1 * we2v[1];
      psum[j] = s;
    }
    __syncthreads();
#pragma unroll
    for (int j = 0; j < 4; ++j) red[wave][lk8*4 + j][lrow] = psum[j];
    __syncthreads();
    int r = tid >> 4, c = tid & 15;
    float s2 = red[0][r][c] + red[1][r][c] + red[2][r][c] + red[3][r][c];
    s2 += __shfl_xor(s2, 1); s2 += __shfl_xor(s2, 2);
    s2 += __shfl_xor(s2, 4); s2 += __shfl_xor(s2, 8);
    if (c == 0 && n0 + r < N) epsp1[n0 + r] = 1.0f + s2 + be2v;
  }
}

// ---------------- CSR build: count, hierarchical scan, fill perm ----------------
__global__ void initc_kernel(int* __restrict__ cnt, int N){
  int i = blockIdx.x * 256 + threadIdx.x;
  if (i < N) cnt[i] = 0;
}

__global__ void count_kernel(const int* __restrict__ dst, int* __restrict__ cnt, int E){
  int e = blockIdx.x * 256 + threadIdx.x;
  if (e < E) atomicAdd(&cnt[dst[e]], 1);
}

// block-local exclusive scan; bsum[b] = block total
__global__ void scan1_kernel(const int* __restrict__ cnt, int* __restrict__ off,
                             int* __restrict__ bsum, int N){
  __shared__ int tmp[256];
  int i = blockIdx.x * 256 + threadIdx.x;
  int v = (i < N) ? cnt[i] : 0;
  tmp[threadIdx.x] = v;
  for (int s = 1; s < 256; s <<= 1){
    __syncthreads();
    int t = (threadIdx.x >= s) ? tmp[threadIdx.x - s] : 0;
    __syncthreads();
    tmp[threadIdx.x] += t;
  }
  __syncthreads();
  if (i < N) off[i] = tmp[threadIdx.x] - v;
  if (threadIdx.x == 255) bsum[blockIdx.x] = tmp[255];
}

// exclusive scan of block sums (nb <= 256)
__global__ void scan2_kernel(int* __restrict__ bsum, int nb){
  __shared__ int tmp[256];
  int v = (threadIdx.x < nb) ? bsum[threadIdx.x] : 0;
  tmp[threadIdx.x] = v;
  for (int s = 1; s < 256; s <<= 1){
    __syncthreads();
    int t = (threadIdx.x >= s) ? tmp[threadIdx.x - s] : 0;
    __syncthreads();
    tmp[threadIdx.x] += t;
  }
  __syncthreads();
  if (threadIdx.x < nb) bsum[threadIdx.x] = tmp[threadIdx.x] - v;
}

__global__ void scan3_kernel(int* __restrict__ off, const int* __restrict__ bsum,
                             int* __restrict__ cursor, const int* __restrict__ cnt,
                             int N, int E){
  int i = blockIdx.x * 256 + threadIdx.x;
  if (i < N){
    int o = off[i] + bsum[blockIdx.x];
    off[i] = o; cursor[i] = o;
    if (i == N - 1) off[N] = E;
  }
}

__global__ void fill_kernel(const int* __restrict__ dst, int* __restrict__ cursor,
                            int* __restrict__ perm, int E){
  int e = blockIdx.x * 256 + threadIdx.x;
  if (e >= E) return;
  int pos = atomicAdd(&cursor[dst[e]], 1);
  perm[pos] = e;
}

// ---------------- edge GEMM (original order, wave-owned tiles, no barriers) ----------------
// exv[e] = exp( min( relu(gh[e]@W + Psrc[src]+Pdst[dst]+ba1).Wa2 + ba2, 80 ) )
__global__ __launch_bounds__(256) void edge_gemm3_kernel(
    const float* __restrict__ gh, const short* __restrict__ Wt,
    const float* __restrict__ Psrc, const float* __restrict__ Pdst,
    const int* __restrict__ src, const int* __restrict__ dst,
    const float* __restrict__ ba1, const float* __restrict__ Wa2, const float* __restrict__ ba2,
    float* __restrict__ exv, int E)
{
  __shared__ short wlds[F*F];          // 32 KB, XOR-swizzled
  int tid = threadIdx.x;
  for (int i = tid; i < F*16; i += 256){
    int row = i >> 4, o16 = i & 15;
    s16x8 v = *(const s16x8*)(Wt + (size_t)row*F + o16*8);
    *(s16x8*)((char*)wlds + row*256 + ((o16*16) ^ ((row & 7) << 4))) = v;
  }
  __syncthreads();

  int wave = tid >> 6, lane = tid & 63;
  int lrow = lane & 15, lk8 = lane >> 4;
  int sw = (lrow & 7) << 4;

  float wa2v[8], ba1v[8];
#pragma unroll
  for (int cg = 0; cg < 8; ++cg){
    wa2v[cg] = Wa2[cg*16 + lrow];
    ba1v[cg] = ba1[cg*16 + lrow];
  }
  float ba2v = ba2[0];

  int ntiles = (E + 15) >> 4;
  int gw = blockIdx.x * 4 + wave, nw = gridDim.x * 4;
  for (int t = gw; t < ntiles; t += nw){
    int p0 = t * 16;
    int ar = p0 + lrow; if (ar >= E) ar = E - 1;
    const float* gp = gh + (size_t)ar*F;
    s16x8 afr[4];
#pragma unroll
    for (int kc = 0; kc < 4; ++kc){
      float4 x0 = *(const float4*)(gp + kc*32 + lk8*8);
      float4 x1 = *(const float4*)(gp + kc*32 + lk8*8 + 4);
      s16x8 a;
      a[0]=f2bf(x0.x); a[1]=f2bf(x0.y); a[2]=f2bf(x0.z); a[3]=f2bf(x0.w);
      a[4]=f2bf(x1.x); a[5]=f2bf(x1.y); a[6]=f2bf(x1.z); a[7]=f2bf(x1.w);
      afr[kc] = a;
    }

    int sIdx[4], dIdx[4];
#pragma unroll
    for (int j = 0; j < 4; ++j){
      int p = p0 + lk8*4 + j; int pc = (p < E) ? p : E - 1;
      sIdx[j] = src[pc]; dIdx[j] = dst[pc];
    }

    float colsum[4] = {0.f, 0.f, 0.f, 0.f};
#pragma unroll
    for (int cg = 0; cg < 8; cg += 2){
      float ps0[4], pd0[4], ps1[4], pd1[4];
#pragma unroll
      for (int j = 0; j < 4; ++j){
        ps0[j] = Psrc[(size_t)sIdx[j]*F +  cg   *16 + lrow];
        pd0[j] = Pdst[(size_t)dIdx[j]*F +  cg   *16 + lrow];
        ps1[j] = Psrc[(size_t)sIdx[j]*F + (cg+1)*16 + lrow];
        pd1[j] = Pdst[(size_t)dIdx[j]*F + (cg+1)*16 + lrow];
      }
      int col0 = cg*16 + lrow, col1 = col0 + 16;
      const char* wb0 = (const char*)wlds + col0*256;
      const char* wb1 = (const char*)wlds + col1*256;
      s16x8 b0 = *(const s16x8*)(wb0 + ((  0 + lk8*16) ^ sw));
      s16x8 b1 = *(const s16x8*)(wb0 + (( 64 + lk8*16) ^ sw));
      s16x8 b2 = *(const s16x8*)(wb0 + ((128 + lk8*16) ^ sw));
      s16x8 b3 = *(const s16x8*)(wb0 + ((192 + lk8*16) ^ sw));
      s16x8 c0 = *(const s16x8*)(wb1 + ((  0 + lk8*16) ^ sw));
      s16x8 c1 = *(const s16x8*)(wb1 + (( 64 + lk8*16) ^ sw));
      s16x8 c2 = *(const s16x8*)(wb1 + ((128 + lk8*16) ^ sw));
      s16x8 c3 = *(const s16x8*)(wb1 + ((192 + lk8*16) ^ sw));
      f32x4 accA = {0,0,0,0}, accB = {0,0,0,0};
      accA = __builtin_amdgcn_mfma_f32_16x16x32_bf16(afr[0], b0, accA, 0,0,0);
      accB = __builtin_amdgcn_mfma_f32_16x16x32_bf16(afr[0], c0, accB, 0,0,0);
      accA = __builtin_amdgcn_mfma_f32_16x16x32_bf16(afr[1], b1, accA, 0,0,0);
      accB = __builtin_amdgcn_mfma_f32_16x16x32_bf16(afr[1], c1, accB, 0,0,0);
      accA = __builtin_amdgcn_mfma_f32_16x16x32_bf16(afr[2], b2, accA, 0,0,0);
      accB = __builtin_amdgcn_mfma_f32_16x16x32_bf16(afr[2], c2, accB, 0,0,0);
      accA = __builtin_amdgcn_mfma_f32_16x16x32_bf16(afr[3], b3, accA, 0,0,0);
      accB = __builtin_amdgcn_mfma_f32_16x16x32_bf16(afr[3], c3, accB, 0,0,0);
#pragma unroll
      for (int j = 0; j < 4; ++j){
        float h0 = accA[j] + ps0[j] + pd0[j] + ba1v[cg];
        if (h0 > 0.0f) colsum[j] += h0 * wa2v[cg];
        float h1 = accB[j] + ps1[j] + pd1[j] + ba1v[cg+1];
        if (h1 > 0.0f) colsum[j] += h1 * wa2v[cg+1];
      }
    }
#pragma unroll
    for (int j = 0; j < 4; ++j){
      float s = colsum[j];
      s += __shfl_xor(s, 1); s += __shfl_xor(s, 2);
      s += __shfl_xor(s, 4); s += __shfl_xor(s, 8);
      colsum[j] = s;
    }
    if (lrow == 0){
#pragma unroll
      for (int j = 0; j < 4; ++j){
        int p = p0 + lk8*4 + j;
        if (p < E){
          float aval = fminf(colsum[j] + ba2v, 80.0f);  // softmax shift-invariant; a ~ N(0,~0.7)
          exv[p] = __expf(aval);
        }
      }
    }
  }
}

// ---------------- gather + denom + final (single pass over segment) ----------------
__global__ __launch_bounds__(256) void gather_final_kernel(
    const float* __restrict__ gh, const float* __restrict__ nf,
    const int* __restrict__ src, const int* __restrict__ perm, const int* __restrict__ off,
    const float* __restrict__ exv, const float* __restrict__ epsp1,
    float* __restrict__ out, int N)
{
  int lane = threadIdx.x & 63;
  int n = blockIdx.x * 4 + (threadIdx.x >> 6);
  if (n >= N) return;
  int start = off[n], end = off[n + 1];

  int c = lane * 2;
  float ax = 0.0f, ay = 0.0f, den = 0.0f;
  for (int base = start; base < end; base += 64){
    int idx = base + lane;
    int mye = 0, mysrc = 0; float myex = 0.0f;
    if (idx < end){
      mye = perm[idx];
      mysrc = src[mye];
      myex = exv[mye];
    }
    den += myex;
    int m = end - base; if (m > 64) m = 64;
    for (int it = 0; it < m; ++it){
      float ex = __shfl(myex, it);
      int e    = __shfl(mye, it);
      int srow = __shfl(mysrc, it);
      float2 g = *(const float2*)(gh + (size_t)e*F + c);
      float2 h = *(const float2*)(nf + (size_t)srow*F + c);
      ax += ex * g.x * h.x;
      ay += ex * g.y * h.y;
    }
  }
  den += __shfl_xor(den, 1);  den += __shfl_xor(den, 2);
  den += __shfl_xor(den, 4);  den += __shfl_xor(den, 8);
  den += __shfl_xor(den, 16); den += __shfl_xor(den, 32);
  float rden = (den > 0.0f) ? 1.0f / den : 0.0f;   // deg-0: hv = 0

  float ep = epsp1[n];
  float2 x = *(const float2*)(nf + (size_t)n*F + c);
  float2 o;
  o.x = ep * ax * rden + x.x;
  o.y = ep * ay * rden + x.y;
  *(float2*)(out + (size_t)n*F + c) = o;
}

// =================== launch ===================

extern "C" void kernel_launch(void* const* d_in, const int* in_sizes, int n_in,
                              void* d_out, int out_size, void* d_ws, size_t ws_size,
                              hipStream_t stream)
{
  const float* nf  = (const float*)d_in[0];
  const float* gh  = (const float*)d_in[1];
  const int*   src = (const int*)d_in[2];
  const int*   dst = (const int*)d_in[3];
  const float* Wa1 = (const float*)d_in[4];
  const float* ba1 = (const float*)d_in[5];
  const float* Wa2 = (const float*)d_in[6];
  const float* ba2 = (const float*)d_in[7];
  const float* We1 = (const float*)d_in[8];
  const float* be1 = (const float*)d_in[9];
  const float* We2 = (const float*)d_in[10];
  const float* be2 = (const float*)d_in[11];
  int N = in_sizes[0] / F;
  int E = in_sizes[2];
  float* out = (float*)d_out;

  char* w = (char*)d_ws;
  auto alloc = [&](size_t bytes) -> char* {
    char* p = w; w += (bytes + 255) & ~(size_t)255; return p;
  };
  short* packW  = (short*)alloc((size_t)4*F*F*sizeof(short));
  float* Psrc   = (float*)alloc((size_t)N*F*sizeof(float));
  float* Pdst   = (float*)alloc((size_t)N*F*sizeof(float));
  float* epsp1  = (float*)alloc((size_t)N*sizeof(float));
  int*   cnt    = (int*)  alloc((size_t)N*sizeof(int));
  int*   off    = (int*)  alloc((size_t)(N+1)*sizeof(int));
  int*   cursor = (int*)  alloc((size_t)N*sizeof(int));
  int*   bsum   = (int*)  alloc((size_t)256*sizeof(int));
  int*   perm   = (int*)  alloc((size_t)E*sizeof(int));
  float* exv    = (float*)alloc((size_t)E*sizeof(float));

  int nb = (N + 255) / 256;
  initc_kernel<<<nb, 256, 0, stream>>>(cnt, N);
  count_kernel<<<(E + 255)/256, 256, 0, stream>>>(dst, cnt, E);
  scan1_kernel<<<nb, 256, 0, stream>>>(cnt, off, bsum, N);
  scan2_kernel<<<1, 256, 0, stream>>>(bsum, nb);
  scan3_kernel<<<nb, 256, 0, stream>>>(off, bsum, cursor, cnt, N, E);
  fill_kernel<<<(E + 255)/256, 256, 0, stream>>>(dst, cursor, perm, E);
  pack_kernel<<<dim3(F, 4), F, 0, stream>>>(Wa1, We1, packW);
  node_gemm_kernel<<<512, 256, 0, stream>>>(nf, packW, Psrc, Pdst, epsp1,
                                            be1, We2, be2, N);
  edge_gemm3_kernel<<<2048, 256, 0, stream>>>(gh, packW + (size_t)2*F*F,
                                              Psrc, Pdst, src, dst,
                                              ba1, Wa2, ba2, exv, E);
  gather_final_kernel<<<(N + 3)/4, 256, 0, stream>>>(gh, nf, src, perm, off,
                                                     exv, epsp1, out, N);
}